// Round 2
// baseline (1926.088 us; speedup 1.0000x reference)
//
#include <hip/hip_runtime.h>
#include <math.h>

#define S 1024
#define D 768
#define L 12
#define NH 24
#define QKV_OUT 2304
#define FF1_OUT 1536
#define V_SZ 50304

typedef unsigned short u16;
typedef __attribute__((ext_vector_type(8))) short bf16x8;
typedef __attribute__((ext_vector_type(4))) float f32x4;

__device__ __forceinline__ u16 f2bf(float x) {
    unsigned u = __float_as_uint(x);
    u += 0x7fffu + ((u >> 16) & 1u);
    return (u16)(u >> 16);
}

__device__ __forceinline__ void async_copy16(const void* g, void* l) {
    __builtin_amdgcn_global_load_lds(
        (const __attribute__((address_space(1))) unsigned int*)g,
        (__attribute__((address_space(3))) unsigned int*)l, 16, 0, 0);
}

// ---------------------------------------------------------------- embedding
__global__ __launch_bounds__(256) void embed_kernel(
    const int* __restrict__ tok, const float* __restrict__ ew,
    float* __restrict__ x, u16* __restrict__ xb) {
    int t = blockIdx.x;
    int id = tok[t];
    const float* src = ew + (size_t)id * D;
    for (int d = threadIdx.x; d < D; d += 256) {
        float v = src[d];
        x[(size_t)t * D + d] = v;
        xb[(size_t)t * D + d] = f2bf(v);
    }
}

// ------------------------------------- one-time fp32 -> bf16 convert (flat)
__global__ __launch_bounds__(256) void cvt_bf16_kernel(
    const float* __restrict__ in, u16* __restrict__ out) {
    size_t i = ((size_t)blockIdx.x * 256 + threadIdx.x) * 8;
    float4 a = *(const float4*)(in + i);
    float4 b = *(const float4*)(in + i + 4);
    uint4 o;
    o.x = (unsigned)f2bf(a.x) | ((unsigned)f2bf(a.y) << 16);
    o.y = (unsigned)f2bf(a.z) | ((unsigned)f2bf(a.w) << 16);
    o.z = (unsigned)f2bf(b.x) | ((unsigned)f2bf(b.y) << 16);
    o.w = (unsigned)f2bf(b.z) | ((unsigned)f2bf(b.w) << 16);
    *(uint4*)(out + i) = o;
}

// ------------------------------------------- position scan (parallel, linear)
__global__ __launch_bounds__(256) void pos_scan_kernel(
    const float* __restrict__ h, float* __restrict__ x) {
    const int d = blockIdx.x;
    const int tid = threadIdx.x;
    float a[4], b[4];
    #pragma unroll
    for (int i = 0; i < 4; ++i) {
        int t = tid * 4 + i;
        float g  = h[(size_t)t * FF1_OUT + d];
        float lg = h[(size_t)t * FF1_OUT + D + d];
        a[i] = 1.f / (1.f + __expf(-g));
        b[i] = __expf(lg);
    }
    float A = ((a[0] * a[1]) * a[2]) * a[3];
    float B = ((b[0] * a[1] + b[1]) * a[2] + b[2]) * a[3] + b[3];

    __shared__ float sA[256], sB[256];
    sA[tid] = A; sB[tid] = B;
    __syncthreads();
    #pragma unroll
    for (int off = 1; off < 256; off <<= 1) {
        float selfA = sA[tid], selfB = sB[tid];
        float pA = 1.f, pB = 0.f;
        if (tid >= off) { pA = sA[tid - off]; pB = sB[tid - off]; }
        __syncthreads();
        sA[tid] = pA * selfA;
        sB[tid] = pB * selfA + selfB;
        __syncthreads();
    }
    float R = 1.f;
    if (tid > 0) R = sA[tid - 1] + sB[tid - 1];
    #pragma unroll
    for (int i = 0; i < 4; ++i) {
        R = R * a[i] + b[i];
        x[(size_t)(tid * 4 + i) * D + d] += __logf(R);
    }
}

// ---------------------------------------------------- layernorm (bf16 out)
__global__ __launch_bounds__(256) void ln_kernel(
    const float* __restrict__ in, const float* __restrict__ g,
    const float* __restrict__ b, u16* __restrict__ out) {
    int row = blockIdx.x;
    int tid = threadIdx.x;
    const float* p = in + (size_t)row * D;
    float v0 = p[tid], v1 = p[tid + 256], v2 = p[tid + 512];

    __shared__ float red[8];
    float s = v0 + v1 + v2;
    #pragma unroll
    for (int o = 32; o > 0; o >>= 1) s += __shfl_down(s, o, 64);
    int wave = tid >> 6, lane = tid & 63;
    if (lane == 0) red[wave] = s;
    __syncthreads();
    float mean = (red[0] + red[1] + red[2] + red[3]) * (1.f / (float)D);

    float d0 = v0 - mean, d1 = v1 - mean, d2 = v2 - mean;
    float ss = d0 * d0 + d1 * d1 + d2 * d2;
    #pragma unroll
    for (int o = 32; o > 0; o >>= 1) ss += __shfl_down(ss, o, 64);
    if (lane == 0) red[4 + wave] = ss;
    __syncthreads();
    float var = (red[4] + red[5] + red[6] + red[7]) * (1.f / (float)D);
    float rstd = rsqrtf(var + 1e-5f);

    u16* o = out + (size_t)row * D;
    o[tid]       = f2bf(d0 * rstd * g[tid]       + b[tid]);
    o[tid + 256] = f2bf(d1 * rstd * g[tid + 256] + b[tid + 256]);
    o[tid + 512] = f2bf(d2 * rstd * g[tid + 512] + b[tid + 512]);
}

// ------------------------------------- weight convert+transpose fp32->bf16
__global__ __launch_bounds__(256) void wconv_kernel(
    const float* __restrict__ W, u16* __restrict__ WT, int N) {
    __shared__ float tile[32][33];
    const int z = blockIdx.z;
    W  += (size_t)z * 768 * N;
    WT += (size_t)z * N * 768;
    const int n0 = blockIdx.x * 32, k0 = blockIdx.y * 32;
    const int t = threadIdx.x;
    const int r = t >> 3, c4 = (t & 7) * 4;
    float4 v = *(const float4*)(W + (size_t)(k0 + r) * N + n0 + c4);
    tile[r][c4] = v.x; tile[r][c4 + 1] = v.y; tile[r][c4 + 2] = v.z; tile[r][c4 + 3] = v.w;
    __syncthreads();
    ushort4 o;
    o.x = f2bf(tile[c4][r]);     o.y = f2bf(tile[c4 + 1][r]);
    o.z = f2bf(tile[c4 + 2][r]); o.w = f2bf(tile[c4 + 3][r]);
    *(ushort4*)(WT + (size_t)(n0 + r) * 768 + k0 + c4) = o;
}

// --------------------------- MFMA GEMM, bf16 B, double-buffered 2-phase loop
// Per k-iter: issue next tile's global_load_lds FIRST, then ds_read+MFMA on
// the current tile, then one __syncthreads (its implicit vmcnt(0) drain now
// overlaps the MFMA work instead of serializing with it).
// SWAP: m comes from blockIdx.x (fast dim) so blocks sharing a B n-tile are
// dispatched consecutively -> B fetched ~once from HBM (L3/L2 serve the rest).
template <bool SWAP>
__global__ __launch_bounds__(256) void gemm_bf16_kernel(
    const u16* __restrict__ A, const u16* __restrict__ B,
    const float* __restrict__ bias, const float* __restrict__ Cin,
    float* __restrict__ C, int N) {
    constexpr int K = 768;
    constexpr int NT = K / 32;
    __shared__ __align__(16) u16 As[2][128 * 32];
    __shared__ __align__(16) u16 Bs[2][128 * 32];
    const int tid = threadIdx.x;
    const int w = tid >> 6, lane = tid & 63;
    const int m0 = (SWAP ? blockIdx.x : blockIdx.y) * 128;
    const int n0 = (SWAP ? blockIdx.y : blockIdx.x) * 128;
    const int wm = (w >> 1) * 64, wn = (w & 1) * 64;

    f32x4 acc[4][4] = {};

    const int rA = w * 32 + (lane >> 2);
    const int cA = (lane & 3) * 8;
    const int frow = lane & 15;
    const int fko = (lane >> 4) * 8;

    const u16* gA = A + (size_t)(m0 + rA) * K + cA;
    const u16* gB = B + (size_t)(n0 + rA) * K + cA;

    // prologue: stage tile 0 into buffer 0
    async_copy16(gA, (char*)As[0] + w * 2048);
    async_copy16(gA + (size_t)16 * K, (char*)As[0] + w * 2048 + 1024);
    async_copy16(gB, (char*)Bs[0] + w * 2048);
    async_copy16(gB + (size_t)16 * K, (char*)Bs[0] + w * 2048 + 1024);
    __syncthreads();

    int cur = 0;
    for (int t = 0; t < NT; ++t) {
        if (t + 1 < NT) {
            const u16* a1 = gA + (t + 1) * 32;
            const u16* b1 = gB + (t + 1) * 32;
            async_copy16(a1, (char*)As[cur ^ 1] + w * 2048);
            async_copy16(a1 + (size_t)16 * K, (char*)As[cur ^ 1] + w * 2048 + 1024);
            async_copy16(b1, (char*)Bs[cur ^ 1] + w * 2048);
            async_copy16(b1 + (size_t)16 * K, (char*)Bs[cur ^ 1] + w * 2048 + 1024);
        }
        bf16x8 af[4], bfr[4];
        #pragma unroll
        for (int i = 0; i < 4; ++i)
            af[i] = *(const bf16x8*)(As[cur] + (wm + i * 16 + frow) * 32 + fko);
        #pragma unroll
        for (int j = 0; j < 4; ++j)
            bfr[j] = *(const bf16x8*)(Bs[cur] + (wn + j * 16 + frow) * 32 + fko);
        #pragma unroll
        for (int i = 0; i < 4; ++i)
            #pragma unroll
            for (int j = 0; j < 4; ++j)
                acc[i][j] = __builtin_amdgcn_mfma_f32_16x16x32_bf16(af[i], bfr[j], acc[i][j], 0, 0, 0);
        __syncthreads();
        cur ^= 1;
    }

    const int crow = wm + (lane >> 4) * 4;
    const int ccol = wn + (lane & 15);
    #pragma unroll
    for (int j = 0; j < 4; ++j) {
        int col = n0 + ccol + j * 16;
        float bj = bias ? bias[col] : 0.f;
        #pragma unroll
        for (int i = 0; i < 4; ++i) {
            #pragma unroll
            for (int r = 0; r < 4; ++r) {
                int row = m0 + crow + i * 16 + r;
                size_t off = (size_t)row * N + col;
                float v = acc[i][j][r] + bj;
                if (Cin) v += Cin[off];
                C[off] = v;
            }
        }
    }
}

// ---------------------------------------- fallback GEMM (fp32 B, original)
__global__ __launch_bounds__(256) void gemm_f32b_kernel(
    const u16* __restrict__ A, const float* __restrict__ B,
    const float* __restrict__ bias, const float* __restrict__ Cin,
    float* __restrict__ C, int N) {
    constexpr int K = 768;
    __shared__ __align__(16) u16 As[128 * 32];
    __shared__ __align__(16) u16 Bs[128 * 32];
    const int tid = threadIdx.x;
    const int w = tid >> 6, lane = tid & 63;
    const int m0 = blockIdx.y * 128, n0 = blockIdx.x * 128;
    const int wm = (w >> 1) * 64, wn = (w & 1) * 64;

    f32x4 acc[4][4] = {};

    const int rA = w * 32 + (lane >> 2);
    const int cA = (lane & 3) * 8;
    const int frow = lane & 15;
    const int fko = (lane >> 4) * 8;

    for (int k0 = 0; k0 < K; k0 += 32) {
        {
            const u16* g0 = A + (size_t)(m0 + rA) * K + k0 + cA;
            async_copy16(g0, (char*)As + w * 2048);
            async_copy16(g0 + (size_t)16 * K, (char*)As + w * 2048 + 1024);
        }
        {
            const int r = tid >> 1, half = tid & 1;
            const float* src = B + (size_t)(n0 + r) * K + k0 + half * 16;
            float4 v0 = *(const float4*)(src);
            float4 v1 = *(const float4*)(src + 4);
            float4 v2 = *(const float4*)(src + 8);
            float4 v3 = *(const float4*)(src + 12);
            unsigned p0 = (unsigned)f2bf(v0.x) | ((unsigned)f2bf(v0.y) << 16);
            unsigned p1 = (unsigned)f2bf(v0.z) | ((unsigned)f2bf(v0.w) << 16);
            unsigned p2 = (unsigned)f2bf(v1.x) | ((unsigned)f2bf(v1.y) << 16);
            unsigned p3 = (unsigned)f2bf(v1.z) | ((unsigned)f2bf(v1.w) << 16);
            unsigned p4 = (unsigned)f2bf(v2.x) | ((unsigned)f2bf(v2.y) << 16);
            unsigned p5 = (unsigned)f2bf(v2.z) | ((unsigned)f2bf(v2.w) << 16);
            unsigned p6 = (unsigned)f2bf(v3.x) | ((unsigned)f2bf(v3.y) << 16);
            unsigned p7 = (unsigned)f2bf(v3.z) | ((unsigned)f2bf(v3.w) << 16);
            u16* dst = Bs + r * 32 + half * 16;
            *(uint4*)(dst)     = make_uint4(p0, p1, p2, p3);
            *(uint4*)(dst + 8) = make_uint4(p4, p5, p6, p7);
        }
        __syncthreads();

        bf16x8 af[4], bfr[4];
        #pragma unroll
        for (int i = 0; i < 4; ++i)
            af[i] = *(const bf16x8*)(As + (wm + i * 16 + frow) * 32 + fko);
        #pragma unroll
        for (int j = 0; j < 4; ++j)
            bfr[j] = *(const bf16x8*)(Bs + (wn + j * 16 + frow) * 32 + fko);
        #pragma unroll
        for (int i = 0; i < 4; ++i)
            #pragma unroll
            for (int j = 0; j < 4; ++j)
                acc[i][j] = __builtin_amdgcn_mfma_f32_16x16x32_bf16(af[i], bfr[j], acc[i][j], 0, 0, 0);
        __syncthreads();
    }

    const int crow = wm + (lane >> 4) * 4;
    const int ccol = wn + (lane & 15);
    #pragma unroll
    for (int j = 0; j < 4; ++j) {
        int col = n0 + ccol + j * 16;
        float bj = bias ? bias[col] : 0.f;
        #pragma unroll
        for (int i = 0; i < 4; ++i) {
            #pragma unroll
            for (int r = 0; r < 4; ++r) {
                int row = m0 + crow + i * 16 + r;
                size_t off = (size_t)row * N + col;
                float v = acc[i][j][r] + bj;
                if (Cin) v += Cin[off];
                C[off] = v;
            }
        }
    }
}

// ------------------------------------------------- MFMA flash attention
__global__ __launch_bounds__(256) void attn_kernel(
    const float* __restrict__ y, u16* __restrict__ att) {
    const int tb = blockIdx.x, head = blockIdx.y;
    const int tid = threadIdx.x, w = tid >> 6, lane = tid & 63;
    const int q = lane >> 4, cl = lane & 15;
    const int t0 = tb * 64;

    __shared__ __align__(16) u16 Qs[64 * 32];
    __shared__ __align__(16) u16 Ks[64 * 32];
    __shared__ __align__(16) u16 Vt[32 * 64];
    __shared__ __align__(16) u16 As[4][16 * 64];
    u16* As_w = As[w];

    bf16x8 ones8;
    #pragma unroll
    for (int i = 0; i < 8; ++i) ones8[i] = (short)0x3F80;

    f32x4 accO[2] = {};
    f32x4 accZ = {};

    #pragma unroll
    for (int i = 0; i < 2; ++i) {
        int e = tid + i * 256;
        int row = e >> 3, c4 = (e & 7) * 4;
        float4 v = *(const float4*)(y + (size_t)(t0 + row) * QKV_OUT + head * 96 + c4);
        ushort4 o;
        o.x = f2bf(__expf(v.x)); o.y = f2bf(__expf(v.y));
        o.z = f2bf(__expf(v.z)); o.w = f2bf(__expf(v.w));
        *(ushort4*)(Qs + row * 32 + c4) = o;
    }

    for (int sb = 0; sb <= tb; ++sb) {
        const int s0 = sb * 64;
        #pragma unroll
        for (int i = 0; i < 2; ++i) {
            int e = tid + i * 256;
            int row = e >> 3, c4 = (e & 7) * 4;
            const float* src = y + (size_t)(s0 + row) * QKV_OUT + head * 96;
            float4 kv = *(const float4*)(src + 32 + c4);
            ushort4 o;
            o.x = f2bf(__expf(kv.x)); o.y = f2bf(__expf(kv.y));
            o.z = f2bf(__expf(kv.z)); o.w = f2bf(__expf(kv.w));
            *(ushort4*)(Ks + row * 32 + c4) = o;
            float4 vv = *(const float4*)(src + 64 + c4);
            float ev[4] = {__expf(vv.x), __expf(vv.y), __expf(vv.z), __expf(vv.w)};
            #pragma unroll
            for (int n = 0; n < 4; ++n) {
                int j = c4 + n;
                Vt[j * 64 + (((row >> 4) ^ (j & 3)) * 16) + (row & 15)] = f2bf(ev[n]);
            }
        }
        __syncthreads();

        bf16x8 af_q = *(const bf16x8*)(Qs + (w * 16 + cl) * 32 + q * 8);
        f32x4 aqk[4];
        #pragma unroll
        for (int nt = 0; nt < 4; ++nt) {
            bf16x8 bk = *(const bf16x8*)(Ks + (nt * 16 + cl) * 32 + q * 8);
            aqk[nt] = __builtin_amdgcn_mfma_f32_16x16x32_bf16(af_q, bk, (f32x4){0.f, 0.f, 0.f, 0.f}, 0, 0, 0);
        }
        #pragma unroll
        for (int nt = 0; nt < 4; ++nt) {
            #pragma unroll
            for (int reg = 0; reg < 4; ++reg) {
                int r = q * 4 + reg;
                int tg = t0 + w * 16 + r;
                int cg = s0 + nt * 16 + cl;
                float v = (cg <= tg) ? aqk[nt][reg] : 0.f;
                As_w[r * 64 + ((nt ^ q) * 16) + cl] = f2bf(v);
            }
        }
        bf16x8 af_a[2];
        #pragma unroll
        for (int kt = 0; kt < 2; ++kt) {
            int blk = (kt * 2 + (q >> 1)) ^ (cl >> 2);
            af_a[kt] = *(const bf16x8*)(As_w + cl * 64 + blk * 16 + (q & 1) * 8);
        }
        #pragma unroll
        for (int kt = 0; kt < 2; ++kt)
            accZ = __builtin_amdgcn_mfma_f32_16x16x32_bf16(af_a[kt], ones8, accZ, 0, 0, 0);
        #pragma unroll
        for (int nt = 0; nt < 2; ++nt) {
            #pragma unroll
            for (int kt = 0; kt < 2; ++kt) {
                int j = nt * 16 + cl;
                int blk = (kt * 2 + (q >> 1)) ^ (j & 3);
                bf16x8 bv = *(const bf16x8*)(Vt + j * 64 + blk * 16 + (q & 1) * 8);
                accO[nt] = __builtin_amdgcn_mfma_f32_16x16x32_bf16(af_a[kt], bv, accO[nt], 0, 0, 0);
            }
        }
        __syncthreads();
    }

    #pragma unroll
    for (int nt = 0; nt < 2; ++nt) {
        #pragma unroll
        for (int reg = 0; reg < 4; ++reg) {
            int t = t0 + w * 16 + q * 4 + reg;
            int j = nt * 16 + cl;
            att[(size_t)t * D + head * 32 + j] = f2bf(__logf(accO[nt][reg]) - __logf(accZ[reg]));
        }
    }
}

// --------------------------------------------------------------------- GLU
__global__ __launch_bounds__(256) void glu_kernel(
    const float* __restrict__ z, u16* __restrict__ zg) {
    int idx = blockIdx.x * 256 + threadIdx.x;
    int t = idx / D, d = idx - t * D;
    float a = z[(size_t)t * FF1_OUT + d];
    float g = z[(size_t)t * FF1_OUT + D + d];
    zg[idx] = f2bf(a * (1.f / (1.f + __expf(-g))));
}

// ------------------------------------------------------------------ launch
extern "C" void kernel_launch(void* const* d_in, const int* in_sizes, int n_in,
                              void* d_out, int out_size, void* d_ws, size_t ws_size,
                              hipStream_t stream) {
    const int*   tok     = (const int*)d_in[0];
    const float* embed_w = (const float*)d_in[1];
    const float* pos_w   = (const float*)d_in[2];
    const float* pos_b   = (const float*)d_in[3];
    const float* ln1_g   = (const float*)d_in[4];
    const float* ln1_b   = (const float*)d_in[5];
    const float* qkv_w   = (const float*)d_in[6];
    const float* qkv_b   = (const float*)d_in[7];
    const float* ff_w1   = (const float*)d_in[8];
    const float* ff_b1   = (const float*)d_in[9];
    const float* ff_w2   = (const float*)d_in[10];
    const float* lnf_g   = (const float*)d_in[11];
    const float* lnf_b   = (const float*)d_in[12];
    float* out = (float*)d_out;

    char* base = (char*)d_ws;
    float* X    = (float*)(base);
    u16*   XB   = (u16*)  (base + 3145728);
    float* Y    = (float*)(base + 4718592);
    u16*   LNX  = (u16*)  (base + 14155776);
    u16*   ATT  = (u16*)  (base + 15728640);
    u16*   ZG   = (u16*)  (base + 17301504);
    u16*   posT = (u16*)  (base + 18874368);
    u16*   qkvT = (u16*)  (base + 21233664);
    u16*   ff1T = (u16*)  (base + 63700992);
    u16*   ff2T = (u16*)  (base + 92012544);
    u16*   EBW  = (u16*)  (base + 106168320);
    const bool bf16_head = ws_size >= (size_t)106168320 + 77266944;

    wconv_kernel<<<dim3(48, 24, 1),  256, 0, stream>>>(pos_w, posT, 1536);
    wconv_kernel<<<dim3(72, 24, 12), 256, 0, stream>>>(qkv_w, qkvT, 2304);
    wconv_kernel<<<dim3(48, 24, 12), 256, 0, stream>>>(ff_w1, ff1T, 1536);
    wconv_kernel<<<dim3(24, 24, 12), 256, 0, stream>>>(ff_w2, ff2T, 768);

    embed_kernel<<<S, 256, 0, stream>>>(tok, embed_w, X, XB);

    gemm_bf16_kernel<false><<<dim3(12, 8), 256, 0, stream>>>(XB, posT, pos_b, nullptr, Y, FF1_OUT);
    pos_scan_kernel<<<D, 256, 0, stream>>>(Y, X);

    for (int l = 0; l < L; ++l) {
        ln_kernel<<<S, 256, 0, stream>>>(X, ln1_g + (size_t)l * D, ln1_b + (size_t)l * D, LNX);
        gemm_bf16_kernel<false><<<dim3(18, 8), 256, 0, stream>>>(
            LNX, qkvT + (size_t)l * QKV_OUT * 768, qkv_b + (size_t)l * QKV_OUT, nullptr, Y, QKV_OUT);
        attn_kernel<<<dim3(16, NH), 256, 0, stream>>>(Y, ATT);
        gemm_bf16_kernel<false><<<dim3(12, 8), 256, 0, stream>>>(
            ATT, ff1T + (size_t)l * FF1_OUT * 768, ff_b1 + (size_t)l * FF1_OUT, nullptr, Y, FF1_OUT);
        glu_kernel<<<(S * D) / 256, 256, 0, stream>>>(Y, ZG);
        gemm_bf16_kernel<false><<<dim3(6, 8), 256, 0, stream>>>(
            ZG, ff2T + (size_t)l * D * 768, nullptr, X, X, D);
    }

    ln_kernel<<<S, 256, 0, stream>>>(X, lnf_g, lnf_b, LNX);
    if (bf16_head) {
        // convert right before use so EBW (77 MB) is L3-hot for the LM head
        cvt_bf16_kernel<<<18864, 256, 0, stream>>>(embed_w, EBW);
        gemm_bf16_kernel<true><<<dim3(8, 393), 256, 0, stream>>>(LNX, EBW, nullptr, nullptr, out, V_SZ);
    } else {
        gemm_f32b_kernel<<<dim3(393, 8), 256, 0, stream>>>(LNX, embed_w, nullptr, nullptr, out, V_SZ);
    }
}

// Round 3
// 1913.339 us; speedup vs baseline: 1.0067x; 1.0067x over previous
//
#include <hip/hip_runtime.h>
#include <math.h>

#define S 1024
#define D 768
#define L 12
#define NH 24
#define QKV_OUT 2304
#define FF1_OUT 1536
#define V_SZ 50304

typedef unsigned short u16;
typedef __attribute__((ext_vector_type(8))) short bf16x8;
typedef __attribute__((ext_vector_type(4))) float f32x4;

__device__ __forceinline__ u16 f2bf(float x) {
    unsigned u = __float_as_uint(x);
    u += 0x7fffu + ((u >> 16) & 1u);
    return (u16)(u >> 16);
}

__device__ __forceinline__ void async_copy16(const void* g, void* l) {
    __builtin_amdgcn_global_load_lds(
        (const __attribute__((address_space(1))) unsigned int*)g,
        (__attribute__((address_space(3))) unsigned int*)l, 16, 0, 0);
}

// ---------------------------------------------------------------- embedding
__global__ __launch_bounds__(256) void embed_kernel(
    const int* __restrict__ tok, const float* __restrict__ ew,
    float* __restrict__ x, u16* __restrict__ xb) {
    int t = blockIdx.x;
    int id = tok[t];
    const float* src = ew + (size_t)id * D;
    for (int d = threadIdx.x; d < D; d += 256) {
        float v = src[d];
        x[(size_t)t * D + d] = v;
        xb[(size_t)t * D + d] = f2bf(v);
    }
}

// ------------------------------------- one-time fp32 -> bf16 convert (flat)
__global__ __launch_bounds__(256) void cvt_bf16_kernel(
    const float* __restrict__ in, u16* __restrict__ out) {
    size_t i = ((size_t)blockIdx.x * 256 + threadIdx.x) * 8;
    float4 a = *(const float4*)(in + i);
    float4 b = *(const float4*)(in + i + 4);
    uint4 o;
    o.x = (unsigned)f2bf(a.x) | ((unsigned)f2bf(a.y) << 16);
    o.y = (unsigned)f2bf(a.z) | ((unsigned)f2bf(a.w) << 16);
    o.z = (unsigned)f2bf(b.x) | ((unsigned)f2bf(b.y) << 16);
    o.w = (unsigned)f2bf(b.z) | ((unsigned)f2bf(b.w) << 16);
    *(uint4*)(out + i) = o;
}

// ------------------------------------------- position scan (parallel, linear)
__global__ __launch_bounds__(256) void pos_scan_kernel(
    const float* __restrict__ h, float* __restrict__ x) {
    const int d = blockIdx.x;
    const int tid = threadIdx.x;
    float a[4], b[4];
    #pragma unroll
    for (int i = 0; i < 4; ++i) {
        int t = tid * 4 + i;
        float g  = h[(size_t)t * FF1_OUT + d];
        float lg = h[(size_t)t * FF1_OUT + D + d];
        a[i] = 1.f / (1.f + __expf(-g));
        b[i] = __expf(lg);
    }
    float A = ((a[0] * a[1]) * a[2]) * a[3];
    float B = ((b[0] * a[1] + b[1]) * a[2] + b[2]) * a[3] + b[3];

    __shared__ float sA[256], sB[256];
    sA[tid] = A; sB[tid] = B;
    __syncthreads();
    #pragma unroll
    for (int off = 1; off < 256; off <<= 1) {
        float selfA = sA[tid], selfB = sB[tid];
        float pA = 1.f, pB = 0.f;
        if (tid >= off) { pA = sA[tid - off]; pB = sB[tid - off]; }
        __syncthreads();
        sA[tid] = pA * selfA;
        sB[tid] = pB * selfA + selfB;
        __syncthreads();
    }
    float R = 1.f;
    if (tid > 0) R = sA[tid - 1] + sB[tid - 1];
    #pragma unroll
    for (int i = 0; i < 4; ++i) {
        R = R * a[i] + b[i];
        x[(size_t)(tid * 4 + i) * D + d] += __logf(R);
    }
}

// ---------------------------------------------------- layernorm (bf16 out)
__global__ __launch_bounds__(256) void ln_kernel(
    const float* __restrict__ in, const float* __restrict__ g,
    const float* __restrict__ b, u16* __restrict__ out) {
    int row = blockIdx.x;
    int tid = threadIdx.x;
    const float* p = in + (size_t)row * D;
    float v0 = p[tid], v1 = p[tid + 256], v2 = p[tid + 512];

    __shared__ float red[8];
    float s = v0 + v1 + v2;
    #pragma unroll
    for (int o = 32; o > 0; o >>= 1) s += __shfl_down(s, o, 64);
    int wave = tid >> 6, lane = tid & 63;
    if (lane == 0) red[wave] = s;
    __syncthreads();
    float mean = (red[0] + red[1] + red[2] + red[3]) * (1.f / (float)D);

    float d0 = v0 - mean, d1 = v1 - mean, d2 = v2 - mean;
    float ss = d0 * d0 + d1 * d1 + d2 * d2;
    #pragma unroll
    for (int o = 32; o > 0; o >>= 1) ss += __shfl_down(ss, o, 64);
    if (lane == 0) red[4 + wave] = ss;
    __syncthreads();
    float var = (red[4] + red[5] + red[6] + red[7]) * (1.f / (float)D);
    float rstd = rsqrtf(var + 1e-5f);

    u16* o = out + (size_t)row * D;
    o[tid]       = f2bf(d0 * rstd * g[tid]       + b[tid]);
    o[tid + 256] = f2bf(d1 * rstd * g[tid + 256] + b[tid + 256]);
    o[tid + 512] = f2bf(d2 * rstd * g[tid + 512] + b[tid + 512]);
}

// ------------------------------------- weight convert+transpose fp32->bf16
__global__ __launch_bounds__(256) void wconv_kernel(
    const float* __restrict__ W, u16* __restrict__ WT, int N) {
    __shared__ float tile[32][33];
    const int z = blockIdx.z;
    W  += (size_t)z * 768 * N;
    WT += (size_t)z * N * 768;
    const int n0 = blockIdx.x * 32, k0 = blockIdx.y * 32;
    const int t = threadIdx.x;
    const int r = t >> 3, c4 = (t & 7) * 4;
    float4 v = *(const float4*)(W + (size_t)(k0 + r) * N + n0 + c4);
    tile[r][c4] = v.x; tile[r][c4 + 1] = v.y; tile[r][c4 + 2] = v.z; tile[r][c4 + 3] = v.w;
    __syncthreads();
    ushort4 o;
    o.x = f2bf(tile[c4][r]);     o.y = f2bf(tile[c4 + 1][r]);
    o.z = f2bf(tile[c4 + 2][r]); o.w = f2bf(tile[c4 + 3][r]);
    *(ushort4*)(WT + (size_t)(n0 + r) * 768 + k0 + c4) = o;
}

// ------------------------- MFMA GEMM, bf16 B, single-buffer 2-barrier loop
// XSWZ (LM head only): 1-D grid of 3144 blocks = 393 n-panels x 8 m-blocks.
// Consecutive blocks round-robin XCDs, so give each XCD a contiguous chunk
// of (n-panel-major, m-minor) work: all 8 m-blocks sharing a B n-panel run
// on the SAME XCD -> panel fetched into that L2 once, 7 L2 hits.
template <bool XSWZ>
__global__ __launch_bounds__(256) void gemm_bf16_kernel(
    const u16* __restrict__ A, const u16* __restrict__ B,
    const float* __restrict__ bias, const float* __restrict__ Cin,
    float* __restrict__ C, int N) {
    constexpr int K = 768;
    __shared__ __align__(16) u16 As[128 * 32];
    __shared__ __align__(16) u16 Bs[128 * 32];
    const int tid = threadIdx.x;
    const int w = tid >> 6, lane = tid & 63;
    int m0, n0;
    if (XSWZ) {
        const int lid = blockIdx.x;              // 0..3143
        const int xcd = lid & 7, local = lid >> 3;
        const int work = xcd * 393 + local;      // bijective, 3144 % 8 == 0
        n0 = (work >> 3) * 128;
        m0 = (work & 7) * 128;
    } else {
        m0 = blockIdx.y * 128;
        n0 = blockIdx.x * 128;
    }
    const int wm = (w >> 1) * 64, wn = (w & 1) * 64;

    f32x4 acc[4][4] = {};

    const int rA = w * 32 + (lane >> 2);
    const int cA = (lane & 3) * 8;
    const int frow = lane & 15;
    const int fko = (lane >> 4) * 8;

    for (int k0 = 0; k0 < K; k0 += 32) {
        {
            const u16* g0 = A + (size_t)(m0 + rA) * K + k0 + cA;
            async_copy16(g0, (char*)As + w * 2048);
            async_copy16(g0 + (size_t)16 * K, (char*)As + w * 2048 + 1024);
        }
        {
            const u16* g0 = B + (size_t)(n0 + rA) * K + k0 + cA;
            async_copy16(g0, (char*)Bs + w * 2048);
            async_copy16(g0 + (size_t)16 * K, (char*)Bs + w * 2048 + 1024);
        }
        __syncthreads();

        bf16x8 af[4], bfr[4];
        #pragma unroll
        for (int i = 0; i < 4; ++i)
            af[i] = *(const bf16x8*)(As + (wm + i * 16 + frow) * 32 + fko);
        #pragma unroll
        for (int j = 0; j < 4; ++j)
            bfr[j] = *(const bf16x8*)(Bs + (wn + j * 16 + frow) * 32 + fko);
        #pragma unroll
        for (int i = 0; i < 4; ++i)
            #pragma unroll
            for (int j = 0; j < 4; ++j)
                acc[i][j] = __builtin_amdgcn_mfma_f32_16x16x32_bf16(af[i], bfr[j], acc[i][j], 0, 0, 0);
        __syncthreads();
    }

    const int crow = wm + (lane >> 4) * 4;
    const int ccol = wn + (lane & 15);
    #pragma unroll
    for (int j = 0; j < 4; ++j) {
        int col = n0 + ccol + j * 16;
        float bj = bias ? bias[col] : 0.f;
        #pragma unroll
        for (int i = 0; i < 4; ++i) {
            #pragma unroll
            for (int r = 0; r < 4; ++r) {
                int row = m0 + crow + i * 16 + r;
                size_t off = (size_t)row * N + col;
                float v = acc[i][j][r] + bj;
                if (Cin) v += Cin[off];
                C[off] = v;
            }
        }
    }
}

// ---------------------------------------- fallback GEMM (fp32 B, original)
__global__ __launch_bounds__(256) void gemm_f32b_kernel(
    const u16* __restrict__ A, const float* __restrict__ B,
    const float* __restrict__ bias, const float* __restrict__ Cin,
    float* __restrict__ C, int N) {
    constexpr int K = 768;
    __shared__ __align__(16) u16 As[128 * 32];
    __shared__ __align__(16) u16 Bs[128 * 32];
    const int tid = threadIdx.x;
    const int w = tid >> 6, lane = tid & 63;
    const int m0 = blockIdx.y * 128, n0 = blockIdx.x * 128;
    const int wm = (w >> 1) * 64, wn = (w & 1) * 64;

    f32x4 acc[4][4] = {};

    const int rA = w * 32 + (lane >> 2);
    const int cA = (lane & 3) * 8;
    const int frow = lane & 15;
    const int fko = (lane >> 4) * 8;

    for (int k0 = 0; k0 < K; k0 += 32) {
        {
            const u16* g0 = A + (size_t)(m0 + rA) * K + k0 + cA;
            async_copy16(g0, (char*)As + w * 2048);
            async_copy16(g0 + (size_t)16 * K, (char*)As + w * 2048 + 1024);
        }
        {
            const int r = tid >> 1, half = tid & 1;
            const float* src = B + (size_t)(n0 + r) * K + k0 + half * 16;
            float4 v0 = *(const float4*)(src);
            float4 v1 = *(const float4*)(src + 4);
            float4 v2 = *(const float4*)(src + 8);
            float4 v3 = *(const float4*)(src + 12);
            unsigned p0 = (unsigned)f2bf(v0.x) | ((unsigned)f2bf(v0.y) << 16);
            unsigned p1 = (unsigned)f2bf(v0.z) | ((unsigned)f2bf(v0.w) << 16);
            unsigned p2 = (unsigned)f2bf(v1.x) | ((unsigned)f2bf(v1.y) << 16);
            unsigned p3 = (unsigned)f2bf(v1.z) | ((unsigned)f2bf(v1.w) << 16);
            unsigned p4 = (unsigned)f2bf(v2.x) | ((unsigned)f2bf(v2.y) << 16);
            unsigned p5 = (unsigned)f2bf(v2.z) | ((unsigned)f2bf(v2.w) << 16);
            unsigned p6 = (unsigned)f2bf(v3.x) | ((unsigned)f2bf(v3.y) << 16);
            unsigned p7 = (unsigned)f2bf(v3.z) | ((unsigned)f2bf(v3.w) << 16);
            u16* dst = Bs + r * 32 + half * 16;
            *(uint4*)(dst)     = make_uint4(p0, p1, p2, p3);
            *(uint4*)(dst + 8) = make_uint4(p4, p5, p6, p7);
        }
        __syncthreads();

        bf16x8 af[4], bfr[4];
        #pragma unroll
        for (int i = 0; i < 4; ++i)
            af[i] = *(const bf16x8*)(As + (wm + i * 16 + frow) * 32 + fko);
        #pragma unroll
        for (int j = 0; j < 4; ++j)
            bfr[j] = *(const bf16x8*)(Bs + (wn + j * 16 + frow) * 32 + fko);
        #pragma unroll
        for (int i = 0; i < 4; ++i)
            #pragma unroll
            for (int j = 0; j < 4; ++j)
                acc[i][j] = __builtin_amdgcn_mfma_f32_16x16x32_bf16(af[i], bfr[j], acc[i][j], 0, 0, 0);
        __syncthreads();
    }

    const int crow = wm + (lane >> 4) * 4;
    const int ccol = wn + (lane & 15);
    #pragma unroll
    for (int j = 0; j < 4; ++j) {
        int col = n0 + ccol + j * 16;
        float bj = bias ? bias[col] : 0.f;
        #pragma unroll
        for (int i = 0; i < 4; ++i) {
            #pragma unroll
            for (int r = 0; r < 4; ++r) {
                int row = m0 + crow + i * 16 + r;
                size_t off = (size_t)row * N + col;
                float v = acc[i][j][r] + bj;
                if (Cin) v += Cin[off];
                C[off] = v;
            }
        }
    }
}

// --------------------- precompute exp(K),exp(V) as bf16 once per layer
// K and V are contiguous in y (head offsets +32..+96), so EKV[t][h][0..64]
// = exp(y[t][h*96+32 .. h*96+96]). Saves re-reading fp32 + re-expf per tile.
__global__ __launch_bounds__(256) void ekv_kernel(
    const float* __restrict__ y, u16* __restrict__ ekv) {
    const int t = blockIdx.x;
    #pragma unroll
    for (int i = 0; i < 2; ++i) {
        int e = threadIdx.x + i * 256;
        int off = e * 4;
        if (off < NH * 64) {
            int h = off >> 6, c = off & 63;
            float4 v = *(const float4*)(y + (size_t)t * QKV_OUT + h * 96 + 32 + c);
            ushort4 o;
            o.x = f2bf(__expf(v.x)); o.y = f2bf(__expf(v.y));
            o.z = f2bf(__expf(v.z)); o.w = f2bf(__expf(v.w));
            *(ushort4*)(ekv + (size_t)t * (NH * 64) + off) = o;
        }
    }
}

// ------------------------------------------------- MFMA flash attention
__global__ __launch_bounds__(256) void attn_kernel(
    const float* __restrict__ y, const u16* __restrict__ ekv,
    u16* __restrict__ att) {
    const int tb = blockIdx.x, head = blockIdx.y;
    const int tid = threadIdx.x, w = tid >> 6, lane = tid & 63;
    const int q = lane >> 4, cl = lane & 15;
    const int t0 = tb * 64;

    __shared__ __align__(16) u16 Qs[64 * 32];
    __shared__ __align__(16) u16 Ks[64 * 32];
    __shared__ __align__(16) u16 Vt[32 * 64];
    __shared__ __align__(16) u16 As[4][16 * 64];
    u16* As_w = As[w];

    bf16x8 ones8;
    #pragma unroll
    for (int i = 0; i < 8; ++i) ones8[i] = (short)0x3F80;

    f32x4 accO[2] = {};
    f32x4 accZ = {};

    #pragma unroll
    for (int i = 0; i < 2; ++i) {
        int e = tid + i * 256;
        int row = e >> 3, c4 = (e & 7) * 4;
        float4 v = *(const float4*)(y + (size_t)(t0 + row) * QKV_OUT + head * 96 + c4);
        ushort4 o;
        o.x = f2bf(__expf(v.x)); o.y = f2bf(__expf(v.y));
        o.z = f2bf(__expf(v.z)); o.w = f2bf(__expf(v.w));
        *(ushort4*)(Qs + row * 32 + c4) = o;
    }

    for (int sb = 0; sb <= tb; ++sb) {
        const int s0 = sb * 64;
        // stage eK row-major, eV transposed+swizzled (bf16 in, no expf)
        #pragma unroll
        for (int i = 0; i < 2; ++i) {
            int e = tid + i * 256;
            int row = e >> 3, c4 = (e & 7) * 4;
            const u16* src = ekv + (size_t)(s0 + row) * (NH * 64) + head * 64;
            ushort4 k4 = *(const ushort4*)(src + c4);
            *(ushort4*)(Ks + row * 32 + c4) = k4;
            ushort4 v4 = *(const ushort4*)(src + 32 + c4);
            u16 vv[4] = {v4.x, v4.y, v4.z, v4.w};
            #pragma unroll
            for (int n = 0; n < 4; ++n) {
                int j = c4 + n;
                Vt[j * 64 + (((row >> 4) ^ (j & 3)) * 16) + (row & 15)] = vv[n];
            }
        }
        __syncthreads();

        bf16x8 af_q = *(const bf16x8*)(Qs + (w * 16 + cl) * 32 + q * 8);
        f32x4 aqk[4];
        #pragma unroll
        for (int nt = 0; nt < 4; ++nt) {
            bf16x8 bk = *(const bf16x8*)(Ks + (nt * 16 + cl) * 32 + q * 8);
            aqk[nt] = __builtin_amdgcn_mfma_f32_16x16x32_bf16(af_q, bk, (f32x4){0.f, 0.f, 0.f, 0.f}, 0, 0, 0);
        }
        #pragma unroll
        for (int nt = 0; nt < 4; ++nt) {
            #pragma unroll
            for (int reg = 0; reg < 4; ++reg) {
                int r = q * 4 + reg;
                int tg = t0 + w * 16 + r;
                int cg = s0 + nt * 16 + cl;
                float v = (cg <= tg) ? aqk[nt][reg] : 0.f;
                As_w[r * 64 + ((nt ^ q) * 16) + cl] = f2bf(v);
            }
        }
        bf16x8 af_a[2];
        #pragma unroll
        for (int kt = 0; kt < 2; ++kt) {
            int blk = (kt * 2 + (q >> 1)) ^ (cl >> 2);
            af_a[kt] = *(const bf16x8*)(As_w + cl * 64 + blk * 16 + (q & 1) * 8);
        }
        #pragma unroll
        for (int kt = 0; kt < 2; ++kt)
            accZ = __builtin_amdgcn_mfma_f32_16x16x32_bf16(af_a[kt], ones8, accZ, 0, 0, 0);
        #pragma unroll
        for (int nt = 0; nt < 2; ++nt) {
            #pragma unroll
            for (int kt = 0; kt < 2; ++kt) {
                int j = nt * 16 + cl;
                int blk = (kt * 2 + (q >> 1)) ^ (j & 3);
                bf16x8 bv = *(const bf16x8*)(Vt + j * 64 + blk * 16 + (q & 1) * 8);
                accO[nt] = __builtin_amdgcn_mfma_f32_16x16x32_bf16(af_a[kt], bv, accO[nt], 0, 0, 0);
            }
        }
        __syncthreads();
    }

    #pragma unroll
    for (int nt = 0; nt < 2; ++nt) {
        #pragma unroll
        for (int reg = 0; reg < 4; ++reg) {
            int t = t0 + w * 16 + q * 4 + reg;
            int j = nt * 16 + cl;
            att[(size_t)t * D + head * 32 + j] = f2bf(__logf(accO[nt][reg]) - __logf(accZ[reg]));
        }
    }
}

// --------------------------------------------------------------------- GLU
__global__ __launch_bounds__(256) void glu_kernel(
    const float* __restrict__ z, u16* __restrict__ zg) {
    int idx = blockIdx.x * 256 + threadIdx.x;
    int t = idx / D, d = idx - t * D;
    float a = z[(size_t)t * FF1_OUT + d];
    float g = z[(size_t)t * FF1_OUT + D + d];
    zg[idx] = f2bf(a * (1.f / (1.f + __expf(-g))));
}

// ------------------------------------------------------------------ launch
extern "C" void kernel_launch(void* const* d_in, const int* in_sizes, int n_in,
                              void* d_out, int out_size, void* d_ws, size_t ws_size,
                              hipStream_t stream) {
    const int*   tok     = (const int*)d_in[0];
    const float* embed_w = (const float*)d_in[1];
    const float* pos_w   = (const float*)d_in[2];
    const float* pos_b   = (const float*)d_in[3];
    const float* ln1_g   = (const float*)d_in[4];
    const float* ln1_b   = (const float*)d_in[5];
    const float* qkv_w   = (const float*)d_in[6];
    const float* qkv_b   = (const float*)d_in[7];
    const float* ff_w1   = (const float*)d_in[8];
    const float* ff_b1   = (const float*)d_in[9];
    const float* ff_w2   = (const float*)d_in[10];
    const float* lnf_g   = (const float*)d_in[11];
    const float* lnf_b   = (const float*)d_in[12];
    float* out = (float*)d_out;

    char* base = (char*)d_ws;
    float* X    = (float*)(base);
    u16*   XB   = (u16*)  (base + 3145728);
    float* Y    = (float*)(base + 4718592);
    u16*   LNX  = (u16*)  (base + 14155776);
    u16*   ATT  = (u16*)  (base + 15728640);
    u16*   ZG   = (u16*)  (base + 17301504);
    u16*   posT = (u16*)  (base + 18874368);
    u16*   qkvT = (u16*)  (base + 21233664);
    u16*   ff1T = (u16*)  (base + 63700992);
    u16*   ff2T = (u16*)  (base + 92012544);
    // EBW region (77 MB) is only needed after the layer loop; EKV (3.1 MB)
    // borrows its start during the loop and is overwritten by cvt afterwards.
    u16*   EBW  = (u16*)  (base + 106168320);
    u16*   EKV  = (u16*)  (base + 106168320);
    const bool bf16_head = ws_size >= (size_t)106168320 + 77266944;

    wconv_kernel<<<dim3(48, 24, 1),  256, 0, stream>>>(pos_w, posT, 1536);
    wconv_kernel<<<dim3(72, 24, 12), 256, 0, stream>>>(qkv_w, qkvT, 2304);
    wconv_kernel<<<dim3(48, 24, 12), 256, 0, stream>>>(ff_w1, ff1T, 1536);
    wconv_kernel<<<dim3(24, 24, 12), 256, 0, stream>>>(ff_w2, ff2T, 768);

    embed_kernel<<<S, 256, 0, stream>>>(tok, embed_w, X, XB);

    gemm_bf16_kernel<false><<<dim3(12, 8), 256, 0, stream>>>(XB, posT, pos_b, nullptr, Y, FF1_OUT);
    pos_scan_kernel<<<D, 256, 0, stream>>>(Y, X);

    for (int l = 0; l < L; ++l) {
        ln_kernel<<<S, 256, 0, stream>>>(X, ln1_g + (size_t)l * D, ln1_b + (size_t)l * D, LNX);
        gemm_bf16_kernel<false><<<dim3(18, 8), 256, 0, stream>>>(
            LNX, qkvT + (size_t)l * QKV_OUT * 768, qkv_b + (size_t)l * QKV_OUT, nullptr, Y, QKV_OUT);
        ekv_kernel<<<S, 256, 0, stream>>>(Y, EKV);
        attn_kernel<<<dim3(16, NH), 256, 0, stream>>>(Y, EKV, ATT);
        gemm_bf16_kernel<false><<<dim3(12, 8), 256, 0, stream>>>(
            ATT, ff1T + (size_t)l * FF1_OUT * 768, ff_b1 + (size_t)l * FF1_OUT, nullptr, Y, FF1_OUT);
        glu_kernel<<<(S * D) / 256, 256, 0, stream>>>(Y, ZG);
        gemm_bf16_kernel<false><<<dim3(6, 8), 256, 0, stream>>>(
            ZG, ff2T + (size_t)l * D * 768, nullptr, X, X, D);
    }

    ln_kernel<<<S, 256, 0, stream>>>(X, lnf_g, lnf_b, LNX);
    if (bf16_head) {
        cvt_bf16_kernel<<<18864, 256, 0, stream>>>(embed_w, EBW);
        gemm_bf16_kernel<true><<<dim3(3144), 256, 0, stream>>>(LNX, EBW, nullptr, nullptr, out, V_SZ);
    } else {
        gemm_f32b_kernel<<<dim3(393, 8), 256, 0, stream>>>(LNX, embed_w, nullptr, nullptr, out, V_SZ);
    }
}

// Round 4
// 1623.211 us; speedup vs baseline: 1.1866x; 1.1787x over previous
//
#include <hip/hip_runtime.h>
#include <math.h>

#define S 1024
#define D 768
#define L 12
#define NH 24
#define QKV_OUT 2304
#define FF1_OUT 1536
#define V_SZ 50304

typedef unsigned short u16;
typedef __attribute__((ext_vector_type(8))) short bf16x8;
typedef __attribute__((ext_vector_type(4))) float f32x4;

__device__ __forceinline__ u16 f2bf(float x) {
    unsigned u = __float_as_uint(x);
    u += 0x7fffu + ((u >> 16) & 1u);
    return (u16)(u >> 16);
}

__device__ __forceinline__ void async_copy16(const void* g, void* l) {
    __builtin_amdgcn_global_load_lds(
        (const __attribute__((address_space(1))) unsigned int*)g,
        (__attribute__((address_space(3))) unsigned int*)l, 16, 0, 0);
}

// ---------------------------------------------------------------- embedding
__global__ __launch_bounds__(256) void embed_kernel(
    const int* __restrict__ tok, const float* __restrict__ ew,
    float* __restrict__ x, u16* __restrict__ xb) {
    int t = blockIdx.x;
    int id = tok[t];
    const float* src = ew + (size_t)id * D;
    for (int d = threadIdx.x; d < D; d += 256) {
        float v = src[d];
        x[(size_t)t * D + d] = v;
        xb[(size_t)t * D + d] = f2bf(v);
    }
}

// ------------------------------------- one-time fp32 -> bf16 convert (flat)
__global__ __launch_bounds__(256) void cvt_bf16_kernel(
    const float* __restrict__ in, u16* __restrict__ out) {
    size_t i = ((size_t)blockIdx.x * 256 + threadIdx.x) * 8;
    float4 a = *(const float4*)(in + i);
    float4 b = *(const float4*)(in + i + 4);
    uint4 o;
    o.x = (unsigned)f2bf(a.x) | ((unsigned)f2bf(a.y) << 16);
    o.y = (unsigned)f2bf(a.z) | ((unsigned)f2bf(a.w) << 16);
    o.z = (unsigned)f2bf(b.x) | ((unsigned)f2bf(b.y) << 16);
    o.w = (unsigned)f2bf(b.z) | ((unsigned)f2bf(b.w) << 16);
    *(uint4*)(out + i) = o;
}

// ------------------------------------------- position scan (parallel, linear)
__global__ __launch_bounds__(256) void pos_scan_kernel(
    const float* __restrict__ h, float* __restrict__ x) {
    const int d = blockIdx.x;
    const int tid = threadIdx.x;
    float a[4], b[4];
    #pragma unroll
    for (int i = 0; i < 4; ++i) {
        int t = tid * 4 + i;
        float g  = h[(size_t)t * FF1_OUT + d];
        float lg = h[(size_t)t * FF1_OUT + D + d];
        a[i] = 1.f / (1.f + __expf(-g));
        b[i] = __expf(lg);
    }
    float A = ((a[0] * a[1]) * a[2]) * a[3];
    float B = ((b[0] * a[1] + b[1]) * a[2] + b[2]) * a[3] + b[3];

    __shared__ float sA[256], sB[256];
    sA[tid] = A; sB[tid] = B;
    __syncthreads();
    #pragma unroll
    for (int off = 1; off < 256; off <<= 1) {
        float selfA = sA[tid], selfB = sB[tid];
        float pA = 1.f, pB = 0.f;
        if (tid >= off) { pA = sA[tid - off]; pB = sB[tid - off]; }
        __syncthreads();
        sA[tid] = pA * selfA;
        sB[tid] = pB * selfA + selfB;
        __syncthreads();
    }
    float R = 1.f;
    if (tid > 0) R = sA[tid - 1] + sB[tid - 1];
    #pragma unroll
    for (int i = 0; i < 4; ++i) {
        R = R * a[i] + b[i];
        x[(size_t)(tid * 4 + i) * D + d] += __logf(R);
    }
}

// ---------------------------------------------------- layernorm (bf16 out)
__global__ __launch_bounds__(256) void ln_kernel(
    const float* __restrict__ in, const float* __restrict__ g,
    const float* __restrict__ b, u16* __restrict__ out) {
    int row = blockIdx.x;
    int tid = threadIdx.x;
    const float* p = in + (size_t)row * D;
    float v0 = p[tid], v1 = p[tid + 256], v2 = p[tid + 512];

    __shared__ float red[8];
    float s = v0 + v1 + v2;
    #pragma unroll
    for (int o = 32; o > 0; o >>= 1) s += __shfl_down(s, o, 64);
    int wave = tid >> 6, lane = tid & 63;
    if (lane == 0) red[wave] = s;
    __syncthreads();
    float mean = (red[0] + red[1] + red[2] + red[3]) * (1.f / (float)D);

    float d0 = v0 - mean, d1 = v1 - mean, d2 = v2 - mean;
    float ss = d0 * d0 + d1 * d1 + d2 * d2;
    #pragma unroll
    for (int o = 32; o > 0; o >>= 1) ss += __shfl_down(ss, o, 64);
    if (lane == 0) red[4 + wave] = ss;
    __syncthreads();
    float var = (red[4] + red[5] + red[6] + red[7]) * (1.f / (float)D);
    float rstd = rsqrtf(var + 1e-5f);

    u16* o = out + (size_t)row * D;
    o[tid]       = f2bf(d0 * rstd * g[tid]       + b[tid]);
    o[tid + 256] = f2bf(d1 * rstd * g[tid + 256] + b[tid + 256]);
    o[tid + 512] = f2bf(d2 * rstd * g[tid + 512] + b[tid + 512]);
}

// ------------------------------------- weight convert+transpose fp32->bf16
__global__ __launch_bounds__(256) void wconv_kernel(
    const float* __restrict__ W, u16* __restrict__ WT, int N) {
    __shared__ float tile[32][33];
    const int z = blockIdx.z;
    W  += (size_t)z * 768 * N;
    WT += (size_t)z * N * 768;
    const int n0 = blockIdx.x * 32, k0 = blockIdx.y * 32;
    const int t = threadIdx.x;
    const int r = t >> 3, c4 = (t & 7) * 4;
    float4 v = *(const float4*)(W + (size_t)(k0 + r) * N + n0 + c4);
    tile[r][c4] = v.x; tile[r][c4 + 1] = v.y; tile[r][c4 + 2] = v.z; tile[r][c4 + 3] = v.w;
    __syncthreads();
    ushort4 o;
    o.x = f2bf(tile[c4][r]);     o.y = f2bf(tile[c4 + 1][r]);
    o.z = f2bf(tile[c4 + 2][r]); o.w = f2bf(tile[c4 + 3][r]);
    *(ushort4*)(WT + (size_t)(n0 + r) * 768 + k0 + c4) = o;
}

// -------------------------------------------------------------- MFMA GEMM
// BMxBN tile, 4 waves in 2x2 arrangement, single-buffer 2-barrier k-loop.
// GLUA:   A = glu(Y) computed on the fly from fp32 Y (stride FF1_OUT);
//         fuses the GLU pass into ff2's A-staging (no ZG buffer).
// EXPOUT: epilogue writes only E = f2bf(expf(acc+bias)) (bf16), no fp32 C;
//         fuses exp-feature computation into the qkv GEMM (no ekv pass).
template <int BM, int BN, bool GLUA, bool EXPOUT>
__global__ __launch_bounds__(256) void gemm_bf16_kernel(
    const u16* __restrict__ A, const float* __restrict__ Af,
    const u16* __restrict__ B, const float* __restrict__ bias,
    const float* __restrict__ Cin, float* __restrict__ C,
    u16* __restrict__ E, int N) {
    constexpr int K = 768;
    constexpr int MI = BM / 32;   // m-fragments per wave (2 waves split BM)
    constexpr int NI = BN / 32;   // n-fragments per wave (2 waves split BN)
    __shared__ __align__(16) u16 As[BM * 32];
    __shared__ __align__(16) u16 Bs[BN * 32];
    const int tid = threadIdx.x;
    const int w = tid >> 6, lane = tid & 63;
    const int m0 = blockIdx.y * BM, n0 = blockIdx.x * BN;
    const int wm = (w >> 1) * (BM / 2);
    const int wn = (w & 1) * (BN / 2);

    f32x4 acc[MI][NI] = {};
    const int frow = lane & 15;
    const int fko = (lane >> 4) * 8;

    for (int k0 = 0; k0 < K; k0 += 32) {
        if constexpr (GLUA) {
            // 64x32 A tile from fp32 Y: a*sigmoid(g), 8 elems/thread
            const int r = tid >> 2, c8 = (tid & 3) * 8;
            const float* pa = Af + (size_t)(m0 + r) * FF1_OUT + k0 + c8;
            float4 a0 = *(const float4*)(pa);
            float4 a1 = *(const float4*)(pa + 4);
            float4 g0 = *(const float4*)(pa + D);
            float4 g1 = *(const float4*)(pa + D + 4);
            float o0 = a0.x / (1.f + __expf(-g0.x));
            float o1 = a0.y / (1.f + __expf(-g0.y));
            float o2 = a0.z / (1.f + __expf(-g0.z));
            float o3 = a0.w / (1.f + __expf(-g0.w));
            float o4 = a1.x / (1.f + __expf(-g1.x));
            float o5 = a1.y / (1.f + __expf(-g1.y));
            float o6 = a1.z / (1.f + __expf(-g1.z));
            float o7 = a1.w / (1.f + __expf(-g1.w));
            uint4 st;
            st.x = (unsigned)f2bf(o0) | ((unsigned)f2bf(o1) << 16);
            st.y = (unsigned)f2bf(o2) | ((unsigned)f2bf(o3) << 16);
            st.z = (unsigned)f2bf(o4) | ((unsigned)f2bf(o5) << 16);
            st.w = (unsigned)f2bf(o6) | ((unsigned)f2bf(o7) << 16);
            *(uint4*)(As + r * 32 + c8) = st;
        } else {
            const int rA = w * (BM / 4) + (lane >> 2);
            const int cA = (lane & 3) * 8;
            const u16* g0 = A + (size_t)(m0 + rA) * K + k0 + cA;
            async_copy16(g0, (char*)As + w * (BM * 16));
            if constexpr (BM == 128)
                async_copy16(g0 + (size_t)16 * K, (char*)As + w * (BM * 16) + 1024);
        }
        {
            const int rB = w * (BN / 4) + (lane >> 2);
            const int cB = (lane & 3) * 8;
            const u16* g0 = B + (size_t)(n0 + rB) * K + k0 + cB;
            async_copy16(g0, (char*)Bs + w * (BN * 16));
            if constexpr (BN == 128)
                async_copy16(g0 + (size_t)16 * K, (char*)Bs + w * (BN * 16) + 1024);
        }
        __syncthreads();

        bf16x8 af[MI], bfr[NI];
        #pragma unroll
        for (int i = 0; i < MI; ++i)
            af[i] = *(const bf16x8*)(As + (wm + i * 16 + frow) * 32 + fko);
        #pragma unroll
        for (int j = 0; j < NI; ++j)
            bfr[j] = *(const bf16x8*)(Bs + (wn + j * 16 + frow) * 32 + fko);
        #pragma unroll
        for (int i = 0; i < MI; ++i)
            #pragma unroll
            for (int j = 0; j < NI; ++j)
                acc[i][j] = __builtin_amdgcn_mfma_f32_16x16x32_bf16(af[i], bfr[j], acc[i][j], 0, 0, 0);
        __syncthreads();
    }

    const int crow4 = (lane >> 4) * 4;
    const int ccol = lane & 15;
    #pragma unroll
    for (int j = 0; j < NI; ++j) {
        int col = n0 + wn + j * 16 + ccol;
        float bj = bias ? bias[col] : 0.f;
        #pragma unroll
        for (int i = 0; i < MI; ++i) {
            #pragma unroll
            for (int r = 0; r < 4; ++r) {
                int row = m0 + wm + i * 16 + crow4 + r;
                size_t off = (size_t)row * N + col;
                float v = acc[i][j][r] + bj;
                if constexpr (EXPOUT) {
                    E[off] = f2bf(__expf(v));
                } else {
                    if (Cin) v += Cin[off];
                    C[off] = v;
                }
            }
        }
    }
}

// ---------------------------------------- fallback GEMM (fp32 B, original)
__global__ __launch_bounds__(256) void gemm_f32b_kernel(
    const u16* __restrict__ A, const float* __restrict__ B,
    const float* __restrict__ bias, const float* __restrict__ Cin,
    float* __restrict__ C, int N) {
    constexpr int K = 768;
    __shared__ __align__(16) u16 As[128 * 32];
    __shared__ __align__(16) u16 Bs[128 * 32];
    const int tid = threadIdx.x;
    const int w = tid >> 6, lane = tid & 63;
    const int m0 = blockIdx.y * 128, n0 = blockIdx.x * 128;
    const int wm = (w >> 1) * 64, wn = (w & 1) * 64;

    f32x4 acc[4][4] = {};

    const int rA = w * 32 + (lane >> 2);
    const int cA = (lane & 3) * 8;
    const int frow = lane & 15;
    const int fko = (lane >> 4) * 8;

    for (int k0 = 0; k0 < K; k0 += 32) {
        {
            const u16* g0 = A + (size_t)(m0 + rA) * K + k0 + cA;
            async_copy16(g0, (char*)As + w * 2048);
            async_copy16(g0 + (size_t)16 * K, (char*)As + w * 2048 + 1024);
        }
        {
            const int r = tid >> 1, half = tid & 1;
            const float* src = B + (size_t)(n0 + r) * K + k0 + half * 16;
            float4 v0 = *(const float4*)(src);
            float4 v1 = *(const float4*)(src + 4);
            float4 v2 = *(const float4*)(src + 8);
            float4 v3 = *(const float4*)(src + 12);
            unsigned p0 = (unsigned)f2bf(v0.x) | ((unsigned)f2bf(v0.y) << 16);
            unsigned p1 = (unsigned)f2bf(v0.z) | ((unsigned)f2bf(v0.w) << 16);
            unsigned p2 = (unsigned)f2bf(v1.x) | ((unsigned)f2bf(v1.y) << 16);
            unsigned p3 = (unsigned)f2bf(v1.z) | ((unsigned)f2bf(v1.w) << 16);
            unsigned p4 = (unsigned)f2bf(v2.x) | ((unsigned)f2bf(v2.y) << 16);
            unsigned p5 = (unsigned)f2bf(v2.z) | ((unsigned)f2bf(v2.w) << 16);
            unsigned p6 = (unsigned)f2bf(v3.x) | ((unsigned)f2bf(v3.y) << 16);
            unsigned p7 = (unsigned)f2bf(v3.z) | ((unsigned)f2bf(v3.w) << 16);
            u16* dst = Bs + r * 32 + half * 16;
            *(uint4*)(dst)     = make_uint4(p0, p1, p2, p3);
            *(uint4*)(dst + 8) = make_uint4(p4, p5, p6, p7);
        }
        __syncthreads();

        bf16x8 af[4], bfr[4];
        #pragma unroll
        for (int i = 0; i < 4; ++i)
            af[i] = *(const bf16x8*)(As + (wm + i * 16 + frow) * 32 + fko);
        #pragma unroll
        for (int j = 0; j < 4; ++j)
            bfr[j] = *(const bf16x8*)(Bs + (wn + j * 16 + frow) * 32 + fko);
        #pragma unroll
        for (int i = 0; i < 4; ++i)
            #pragma unroll
            for (int j = 0; j < 4; ++j)
                acc[i][j] = __builtin_amdgcn_mfma_f32_16x16x32_bf16(af[i], bfr[j], acc[i][j], 0, 0, 0);
        __syncthreads();
    }

    const int crow = wm + (lane >> 4) * 4;
    const int ccol = wn + (lane & 15);
    #pragma unroll
    for (int j = 0; j < 4; ++j) {
        int col = n0 + ccol + j * 16;
        float bj = bias ? bias[col] : 0.f;
        #pragma unroll
        for (int i = 0; i < 4; ++i) {
            #pragma unroll
            for (int r = 0; r < 4; ++r) {
                int row = m0 + crow + i * 16 + r;
                size_t off = (size_t)row * N + col;
                float v = acc[i][j][r] + bj;
                if (Cin) v += Cin[off];
                C[off] = v;
            }
        }
    }
}

// ------------------------------------------------- MFMA flash attention
// All inputs pre-exp'd bf16 in EQKV[t][2304] (Q at h*96, K at +32, V at +64).
__global__ __launch_bounds__(256) void attn_kernel(
    const u16* __restrict__ eq, u16* __restrict__ att) {
    const int tb = blockIdx.x, head = blockIdx.y;
    const int tid = threadIdx.x, w = tid >> 6, lane = tid & 63;
    const int q = lane >> 4, cl = lane & 15;
    const int t0 = tb * 64;

    __shared__ __align__(16) u16 Qs[64 * 32];
    __shared__ __align__(16) u16 Ks[64 * 32];
    __shared__ __align__(16) u16 Vt[32 * 64];
    __shared__ __align__(16) u16 As[4][16 * 64];
    u16* As_w = As[w];

    bf16x8 ones8;
    #pragma unroll
    for (int i = 0; i < 8; ++i) ones8[i] = (short)0x3F80;

    f32x4 accO[2] = {};
    f32x4 accZ = {};

    // stage eQ (once): 64x32 bf16, 8 elems/thread
    {
        int row = tid >> 2, c8 = (tid & 3) * 8;
        *(bf16x8*)(Qs + row * 32 + c8) =
            *(const bf16x8*)(eq + (size_t)(t0 + row) * QKV_OUT + head * 96 + c8);
    }

    for (int sb = 0; sb <= tb; ++sb) {
        const int s0 = sb * 64;
        // stage eK row-major (8 elems/thread)
        {
            int row = tid >> 2, c8 = (tid & 3) * 8;
            *(bf16x8*)(Ks + row * 32 + c8) =
                *(const bf16x8*)(eq + (size_t)(s0 + row) * QKV_OUT + head * 96 + 32 + c8);
        }
        // stage eV transposed+swizzled
        #pragma unroll
        for (int i = 0; i < 2; ++i) {
            int e = tid + i * 256;
            int row = e >> 3, c4 = (e & 7) * 4;
            ushort4 v4 = *(const ushort4*)(eq + (size_t)(s0 + row) * QKV_OUT + head * 96 + 64 + c4);
            u16 vv[4] = {v4.x, v4.y, v4.z, v4.w};
            #pragma unroll
            for (int n = 0; n < 4; ++n) {
                int j = c4 + n;
                Vt[j * 64 + (((row >> 4) ^ (j & 3)) * 16) + (row & 15)] = vv[n];
            }
        }
        __syncthreads();

        bf16x8 af_q = *(const bf16x8*)(Qs + (w * 16 + cl) * 32 + q * 8);
        f32x4 aqk[4];
        #pragma unroll
        for (int nt = 0; nt < 4; ++nt) {
            bf16x8 bk = *(const bf16x8*)(Ks + (nt * 16 + cl) * 32 + q * 8);
            aqk[nt] = __builtin_amdgcn_mfma_f32_16x16x32_bf16(af_q, bk, (f32x4){0.f, 0.f, 0.f, 0.f}, 0, 0, 0);
        }
        #pragma unroll
        for (int nt = 0; nt < 4; ++nt) {
            #pragma unroll
            for (int reg = 0; reg < 4; ++reg) {
                int r = q * 4 + reg;
                int tg = t0 + w * 16 + r;
                int cg = s0 + nt * 16 + cl;
                float v = (cg <= tg) ? aqk[nt][reg] : 0.f;
                As_w[r * 64 + ((nt ^ q) * 16) + cl] = f2bf(v);
            }
        }
        bf16x8 af_a[2];
        #pragma unroll
        for (int kt = 0; kt < 2; ++kt) {
            int blk = (kt * 2 + (q >> 1)) ^ (cl >> 2);
            af_a[kt] = *(const bf16x8*)(As_w + cl * 64 + blk * 16 + (q & 1) * 8);
        }
        #pragma unroll
        for (int kt = 0; kt < 2; ++kt)
            accZ = __builtin_amdgcn_mfma_f32_16x16x32_bf16(af_a[kt], ones8, accZ, 0, 0, 0);
        #pragma unroll
        for (int nt = 0; nt < 2; ++nt) {
            #pragma unroll
            for (int kt = 0; kt < 2; ++kt) {
                int j = nt * 16 + cl;
                int blk = (kt * 2 + (q >> 1)) ^ (j & 3);
                bf16x8 bv = *(const bf16x8*)(Vt + j * 64 + blk * 16 + (q & 1) * 8);
                accO[nt] = __builtin_amdgcn_mfma_f32_16x16x32_bf16(af_a[kt], bv, accO[nt], 0, 0, 0);
            }
        }
        __syncthreads();
    }

    #pragma unroll
    for (int nt = 0; nt < 2; ++nt) {
        #pragma unroll
        for (int reg = 0; reg < 4; ++reg) {
            int t = t0 + w * 16 + q * 4 + reg;
            int j = nt * 16 + cl;
            att[(size_t)t * D + head * 32 + j] = f2bf(__logf(accO[nt][reg]) - __logf(accZ[reg]));
        }
    }
}

// ------------------------------------------------------------------ launch
extern "C" void kernel_launch(void* const* d_in, const int* in_sizes, int n_in,
                              void* d_out, int out_size, void* d_ws, size_t ws_size,
                              hipStream_t stream) {
    const int*   tok     = (const int*)d_in[0];
    const float* embed_w = (const float*)d_in[1];
    const float* pos_w   = (const float*)d_in[2];
    const float* pos_b   = (const float*)d_in[3];
    const float* ln1_g   = (const float*)d_in[4];
    const float* ln1_b   = (const float*)d_in[5];
    const float* qkv_w   = (const float*)d_in[6];
    const float* qkv_b   = (const float*)d_in[7];
    const float* ff_w1   = (const float*)d_in[8];
    const float* ff_b1   = (const float*)d_in[9];
    const float* ff_w2   = (const float*)d_in[10];
    const float* lnf_g   = (const float*)d_in[11];
    const float* lnf_b   = (const float*)d_in[12];
    float* out = (float*)d_out;

    char* base = (char*)d_ws;
    float* X    = (float*)(base);
    u16*   XB   = (u16*)  (base + 3145728);
    float* Y    = (float*)(base + 4718592);
    u16*   LNX  = (u16*)  (base + 14155776);
    u16*   ATT  = (u16*)  (base + 15728640);
    u16*   posT = (u16*)  (base + 18874368);
    u16*   qkvT = (u16*)  (base + 21233664);
    u16*   ff1T = (u16*)  (base + 63700992);
    u16*   ff2T = (u16*)  (base + 92012544);
    // EQKV (4.7 MB) lives at the head of the EBW region during the layer
    // loop; cvt_bf16 overwrites it afterwards (EQKV is dead by then).
    u16*   EQKV = (u16*)  (base + 106168320);
    u16*   EBW  = (u16*)  (base + 106168320);
    const bool bf16_head = ws_size >= (size_t)106168320 + 77266944;

    wconv_kernel<<<dim3(48, 24, 1),  256, 0, stream>>>(pos_w, posT, 1536);
    wconv_kernel<<<dim3(72, 24, 12), 256, 0, stream>>>(qkv_w, qkvT, 2304);
    wconv_kernel<<<dim3(48, 24, 12), 256, 0, stream>>>(ff_w1, ff1T, 1536);
    wconv_kernel<<<dim3(24, 24, 12), 256, 0, stream>>>(ff_w2, ff2T, 768);

    embed_kernel<<<S, 256, 0, stream>>>(tok, embed_w, X, XB);

    gemm_bf16_kernel<64, 64, false, false><<<dim3(24, 16), 256, 0, stream>>>(
        XB, nullptr, posT, pos_b, nullptr, Y, nullptr, FF1_OUT);
    pos_scan_kernel<<<D, 256, 0, stream>>>(Y, X);

    for (int l = 0; l < L; ++l) {
        ln_kernel<<<S, 256, 0, stream>>>(X, ln1_g + (size_t)l * D, ln1_b + (size_t)l * D, LNX);
        gemm_bf16_kernel<64, 64, false, true><<<dim3(36, 16), 256, 0, stream>>>(
            LNX, nullptr, qkvT + (size_t)l * QKV_OUT * 768, qkv_b + (size_t)l * QKV_OUT,
            nullptr, nullptr, EQKV, QKV_OUT);
        attn_kernel<<<dim3(16, NH), 256, 0, stream>>>(EQKV, ATT);
        gemm_bf16_kernel<64, 64, false, false><<<dim3(24, 16), 256, 0, stream>>>(
            ATT, nullptr, ff1T + (size_t)l * FF1_OUT * 768, ff_b1 + (size_t)l * FF1_OUT,
            nullptr, Y, nullptr, FF1_OUT);
        gemm_bf16_kernel<64, 64, true, false><<<dim3(12, 16), 256, 0, stream>>>(
            nullptr, Y, ff2T + (size_t)l * D * 768, nullptr, X, X, nullptr, D);
    }

    ln_kernel<<<S, 256, 0, stream>>>(X, lnf_g, lnf_b, LNX);
    if (bf16_head) {
        cvt_bf16_kernel<<<18864, 256, 0, stream>>>(embed_w, EBW);
        gemm_bf16_kernel<128, 128, false, false><<<dim3(393, 8), 256, 0, stream>>>(
            LNX, nullptr, EBW, nullptr, nullptr, out, nullptr, V_SZ);
    } else {
        gemm_f32b_kernel<<<dim3(393, 8), 256, 0, stream>>>(LNX, embed_w, nullptr, nullptr, out, V_SZ);
    }
}